// Round 5
// baseline (604.831 us; speedup 1.0000x reference)
//
#include <hip/hip_runtime.h>
#include <hip/hip_fp16.h>
#include <math.h>

#define NN 50000
#define EE 800000
#define DD 512
#define HH 256
#define KK 16
#define NB_SCAN 196  // ceil(NN/256)

typedef _Float16 half8_t __attribute__((ext_vector_type(8)));
typedef float f32x4 __attribute__((ext_vector_type(4)));

// ---------------- utility ----------------
__global__ void zero_kernel(int* __restrict__ p, int n) {
    int i = blockIdx.x * blockDim.x + threadIdx.x;
    if (i < n) p[i] = 0;
}

__global__ void count_kernel(const int4* __restrict__ src4, const int4* __restrict__ dst4,
                             int* __restrict__ indeg, int* __restrict__ outdeg) {
    int e = blockIdx.x * blockDim.x + threadIdx.x;
    if (e < EE / 4) {
        int4 s = src4[e], d = dst4[e];
        atomicAdd(&outdeg[s.x], 1); atomicAdd(&outdeg[s.y], 1);
        atomicAdd(&outdeg[s.z], 1); atomicAdd(&outdeg[s.w], 1);
        atomicAdd(&indeg[d.x], 1);  atomicAdd(&indeg[d.y], 1);
        atomicAdd(&indeg[d.z], 1);  atomicAdd(&indeg[d.w], 1);
    }
}

// ---------------- 3-phase multi-block exclusive scan (+node_prep fused in p1) ----------------
__global__ void scan_p1(const int* __restrict__ in, int* __restrict__ part, int n,
                        const int* __restrict__ outdeg, float* __restrict__ dis,
                        float* __restrict__ degf) {
    __shared__ int tile[256];
    int t = threadIdx.x;
    int i = blockIdx.x * 256 + t;
    int v = (i < n) ? in[i] : 0;
    tile[t] = v;
    if (i < n) {
        dis[i]  = 1.0f / sqrtf(1.0f + (float)v);
        degf[i] = (float)outdeg[i];
    }
    __syncthreads();
    for (int o = 128; o > 0; o >>= 1) {
        if (t < o) tile[t] += tile[t + o];
        __syncthreads();
    }
    if (t == 0) part[blockIdx.x] = tile[0];
}

__global__ void scan_p2(int* __restrict__ part, int nb, int* __restrict__ off_end) {
    __shared__ int tile[256];
    int t = threadIdx.x;
    int v = (t < nb) ? part[t] : 0;
    tile[t] = v;
    __syncthreads();
    for (int o = 1; o < 256; o <<= 1) {
        int x = (t >= o) ? tile[t - o] : 0;
        __syncthreads();
        tile[t] += x;
        __syncthreads();
    }
    if (t < nb) part[t] = tile[t] - v;  // exclusive base per block
    if (t == 255) *off_end = tile[255];
}

__global__ void scan_p3(const int* __restrict__ in, const int* __restrict__ part,
                        int* __restrict__ out, int n) {
    __shared__ int tile[256];
    int t = threadIdx.x;
    int i = blockIdx.x * 256 + t;
    int v = (i < n) ? in[i] : 0;
    tile[t] = v;
    __syncthreads();
    for (int o = 1; o < 256; o <<= 1) {
        int x = (t >= o) ? tile[t - o] : 0;
        __syncthreads();
        tile[t] += x;
        __syncthreads();
    }
    if (i < n) out[i] = part[blockIdx.x] + tile[t] - v;
}

__global__ void scatter_kernel(const int4* __restrict__ src4, const int4* __restrict__ dst4,
                               const int* __restrict__ off, int* __restrict__ cur,
                               int* __restrict__ nbr) {
    int e = blockIdx.x * blockDim.x + threadIdx.x;
    if (e < EE / 4) {
        int4 s = src4[e], d = dst4[e];
        int p;
        p = atomicAdd(&cur[d.x], 1); nbr[off[d.x] + p] = s.x;
        p = atomicAdd(&cur[d.y], 1); nbr[off[d.y] + p] = s.y;
        p = atomicAdd(&cur[d.z], 1); nbr[off[d.z] + p] = s.z;
        p = atomicAdd(&cur[d.w], 1); nbr[off[d.w] + p] = s.w;
    }
}

// ---------------- fused weight transpose + f16 convert (W1, W2, Wa) ----------------
// Kept as a SEPARATE kernel immediately before gemm1: the latency-bound GEMM
// depends on Wt1/Wt2 being hot in L2 (r4 post-mortem: fusing this into count
// moved it 5 kernels earlier and cost the GEMM ~15 us).
__global__ void transpose_w(const float* __restrict__ W1, __half* __restrict__ Wt1,
                            const float* __restrict__ W2, __half* __restrict__ Wt2,
                            const float* __restrict__ Wa, __half* __restrict__ WaT) {
    int i = blockIdx.x * 256 + threadIdx.x;
    if (i < DD * HH) {
        int k = i / HH, n = i % HH;
        Wt1[(size_t)n * DD + k] = __float2half(W1[i]);
    } else if (i < DD * HH + HH * HH) {
        int j = i - DD * HH;
        int k = j / HH, n = j % HH;
        Wt2[(size_t)n * HH + k] = __float2half(W2[j]);
    } else if (i < DD * HH + HH * HH + HH * KK) {
        int j = i - DD * HH - HH * HH;
        int k = j / KK, n = j % KK;
        WaT[n * HH + k] = __float2half(Wa[j]);
    }
}

// ---------------- MFMA f16 GEMM: C[M,256] = A[M,KDIM] @ Wt[256,KDIM]^T ----------------
template <typename TA, int KDIM>
__global__ __launch_bounds__(256) void mfma_gemm(const TA* __restrict__ A,
                                                 const __half* __restrict__ Bt,
                                                 __half* __restrict__ C, int M) {
    constexpr bool F32 = sizeof(TA) == 4;
    constexpr int SROW = F32 ? 36 : 40;  // LDS row stride: 2-way bank alias max
    constexpr int EPG  = F32 ? 4 : 8;    // elements per 16B granule
    constexpr int GPR  = 32 / EPG;       // granules per k-row of 32
    constexpr int RPP  = 256 / GPR;      // rows staged per pass
    constexpr int NP   = 128 / RPP;      // staging passes
    constexpr int KI   = KDIM / 32;

    __shared__ TA As[2][128 * SROW];

    int t = threadIdx.x;
    int wave = t >> 6, lane = t & 63, quad = lane >> 4, l16 = lane & 15;
    int row0 = blockIdx.x * 128, col0 = blockIdx.y * 128;
    int wm = (wave & 1) * 64, wn = (wave >> 1) * 64;
    int srow = t / GPR, sg = t % GPR;

    f32x4 acc[4][4] = {};
    uint4 sreg[NP];
    uint4 bcur[4];

    const __half* brow[4];
#pragma unroll
    for (int ni = 0; ni < 4; ni++)
        brow[ni] = Bt + (size_t)(col0 + wn + ni * 16 + l16) * KDIM + quad * 8;

    auto gloadA = [&](int k0) {
#pragma unroll
        for (int p = 0; p < NP; p++) {
            int gr = row0 + p * RPP + srow;
            if (gr < M)
                sreg[p] = *(const uint4*)(A + (size_t)gr * KDIM + k0 + sg * EPG);
            else
                sreg[p] = make_uint4(0, 0, 0, 0);
        }
    };
    auto sstore = [&](int buf) {
#pragma unroll
        for (int p = 0; p < NP; p++)
            *(uint4*)&As[buf][(p * RPP + srow) * SROW + sg * EPG] = sreg[p];
    };

    gloadA(0);
#pragma unroll
    for (int ni = 0; ni < 4; ni++) bcur[ni] = *(const uint4*)(brow[ni]);
    sstore(0);
    __syncthreads();

#pragma unroll
    for (int i = 0; i < KI; i++) {
        int cur = i & 1;
        uint4 bnext[4];
        if (i + 1 < KI) {
            gloadA((i + 1) * 32);
#pragma unroll
            for (int ni = 0; ni < 4; ni++)
                bnext[ni] = *(const uint4*)(brow[ni] + (i + 1) * 32);
        }

        half8_t af[4];
#pragma unroll
        for (int mi = 0; mi < 4; mi++) {
            int row = wm + mi * 16 + l16;
            if constexpr (F32) {
                const float* pl = (const float*)&As[cur][0] + row * SROW + quad * 8;
                float4 x0 = *(const float4*)pl;
                float4 x1 = *(const float4*)(pl + 4);
                half8_t h;
                h[0] = (_Float16)x0.x; h[1] = (_Float16)x0.y;
                h[2] = (_Float16)x0.z; h[3] = (_Float16)x0.w;
                h[4] = (_Float16)x1.x; h[5] = (_Float16)x1.y;
                h[6] = (_Float16)x1.z; h[7] = (_Float16)x1.w;
                af[mi] = h;
            } else {
                af[mi] = *(const half8_t*)&As[cur][row * SROW + quad * 8];
            }
        }
#pragma unroll
        for (int mi = 0; mi < 4; mi++)
#pragma unroll
            for (int ni = 0; ni < 4; ni++)
                acc[mi][ni] = __builtin_amdgcn_mfma_f32_16x16x32_f16(
                    af[mi], *(half8_t*)&bcur[ni], acc[mi][ni], 0, 0, 0);

        if (i + 1 < KI) {
            sstore(cur ^ 1);
#pragma unroll
            for (int ni = 0; ni < 4; ni++) bcur[ni] = bnext[ni];
        }
        __syncthreads();
    }

#pragma unroll
    for (int mi = 0; mi < 4; mi++) {
#pragma unroll
        for (int r = 0; r < 4; r++) {
            int rr = row0 + wm + mi * 16 + quad * 4 + r;
            if (rr < M) {
#pragma unroll
                for (int ni = 0; ni < 4; ni++) {
                    C[(size_t)rr * HH + col0 + wn + ni * 16 + l16] =
                        __float2half(acc[mi][ni][r]);
                }
            }
        }
    }
}

// ---------------- aggregation + bias + SELU (+optional skip) ----------------
__device__ inline void fma8(float* acc, uint4 raw, float w) {
    const __half2* h = (const __half2*)&raw;
#pragma unroll
    for (int i = 0; i < 4; i++) {
        float2 f = __half22float2(h[i]);
        acc[2 * i]     += w * f.x;
        acc[2 * i + 1] += w * f.y;
    }
}

__global__ __launch_bounds__(256) void agg_selu(const __half* __restrict__ T,
                                                const float* __restrict__ dis,
                                                const int* __restrict__ off,
                                                const int* __restrict__ nbr,
                                                const float* __restrict__ bias,
                                                const __half* skip, __half* out) {
    int t = threadIdx.x;
    int l32 = t & 31;
    int n = blockIdx.x * 8 + (t >> 5);
    int c = l32 * 8;
    float dn = dis[n];

    float acc[8];
#pragma unroll
    for (int i = 0; i < 8; i++) acc[i] = 0.f;
    fma8(acc, *(const uint4*)(T + (size_t)n * HH + c), dn * dn);  // self-loop

    int s0 = off[n], s1 = off[n + 1];
    for (int base = s0; base < s1; base += 32) {
        int cnt = min(32, s1 - base);
        int sidv = 0; float sdsv = 0.f;
        if (l32 < cnt) {
            sidv = nbr[base + l32];
            sdsv = dis[sidv] * dn;
        }
        int j = 0;
        for (; j + 8 <= cnt; j += 8) {
            int a0 = __shfl(sidv, j, 32),     a1 = __shfl(sidv, j + 1, 32);
            int a2 = __shfl(sidv, j + 2, 32), a3 = __shfl(sidv, j + 3, 32);
            int a4 = __shfl(sidv, j + 4, 32), a5 = __shfl(sidv, j + 5, 32);
            int a6 = __shfl(sidv, j + 6, 32), a7 = __shfl(sidv, j + 7, 32);
            float w0 = __shfl(sdsv, j, 32),     w1 = __shfl(sdsv, j + 1, 32);
            float w2 = __shfl(sdsv, j + 2, 32), w3 = __shfl(sdsv, j + 3, 32);
            float w4 = __shfl(sdsv, j + 4, 32), w5 = __shfl(sdsv, j + 5, 32);
            float w6 = __shfl(sdsv, j + 6, 32), w7 = __shfl(sdsv, j + 7, 32);
            uint4 r0 = *(const uint4*)(T + (size_t)a0 * HH + c);
            uint4 r1 = *(const uint4*)(T + (size_t)a1 * HH + c);
            uint4 r2 = *(const uint4*)(T + (size_t)a2 * HH + c);
            uint4 r3 = *(const uint4*)(T + (size_t)a3 * HH + c);
            uint4 r4 = *(const uint4*)(T + (size_t)a4 * HH + c);
            uint4 r5 = *(const uint4*)(T + (size_t)a5 * HH + c);
            uint4 r6 = *(const uint4*)(T + (size_t)a6 * HH + c);
            uint4 r7 = *(const uint4*)(T + (size_t)a7 * HH + c);
            fma8(acc, r0, w0); fma8(acc, r1, w1);
            fma8(acc, r2, w2); fma8(acc, r3, w3);
            fma8(acc, r4, w4); fma8(acc, r5, w5);
            fma8(acc, r6, w6); fma8(acc, r7, w7);
        }
        for (; j < cnt; j++) {
            int s = __shfl(sidv, j, 32);
            float w = __shfl(sdsv, j, 32);
            fma8(acc, *(const uint4*)(T + (size_t)s * HH + c), w);
        }
    }

    const float scale = 1.0507009873554805f;
    const float alpha = 1.6732632423543772f;
    float4 b0 = *(const float4*)(bias + c);
    float4 b1 = *(const float4*)(bias + c + 4);
    float bb[8] = {b0.x, b0.y, b0.z, b0.w, b1.x, b1.y, b1.z, b1.w};
    float sk8[8];
#pragma unroll
    for (int i = 0; i < 8; i++) sk8[i] = 0.f;
    if (skip) {
        uint4 raw = *(const uint4*)(skip + (size_t)n * HH + c);
        const __half2* h = (const __half2*)&raw;
#pragma unroll
        for (int i = 0; i < 4; i++) {
            float2 f = __half22float2(h[i]);
            sk8[2 * i] = f.x; sk8[2 * i + 1] = f.y;
        }
    }
    _Float16 res[8];
#pragma unroll
    for (int i = 0; i < 8; i++) {
        float v = acc[i] + bb[i];
        float r = v > 0.f ? scale * v : scale * alpha * expm1f(v);
        res[i] = (_Float16)(r + sk8[i]);
    }
    *(uint4*)(out + (size_t)n * HH + c) = *(uint4*)res;
}

// ---------------- assignment head via MFMA ----------------
// Wave = 64 nodes; logits = Hb[64x256] @ WaT[16x256]^T via 4 mfma per K-step.
__global__ __launch_bounds__(256) void assign_mfma(const __half* __restrict__ Hb,
                                                   const __half* __restrict__ WaT,
                                                   const float* __restrict__ ba,
                                                   const float* __restrict__ degf,
                                                   float* __restrict__ out_assign,
                                                   __half* __restrict__ out_f16,
                                                   float* __restrict__ scal) {
    int t = threadIdx.x;
    int wave = t >> 6, lane = t & 63, quad = lane >> 4, l16 = lane & 15;
    int nb = blockIdx.x * 256 + wave * 64;

    f32x4 acc[4] = {};
    const __half* bp = WaT + l16 * HH + quad * 8;
    const __half* ap[4];
#pragma unroll
    for (int mi = 0; mi < 4; mi++) {
        int r = nb + mi * 16 + l16;
        if (r >= NN) r = NN - 1;
        ap[mi] = Hb + (size_t)r * HH + quad * 8;
    }
#pragma unroll
    for (int s = 0; s < 8; s++) {
        half8_t bf = *(const half8_t*)(bp + s * 32);
#pragma unroll
        for (int mi = 0; mi < 4; mi++) {
            half8_t af = *(const half8_t*)(ap[mi] + s * 32);
            acc[mi] = __builtin_amdgcn_mfma_f32_16x16x32_f16(af, bf, acc[mi], 0, 0, 0);
        }
    }

    float myb = ba[l16];
    float lcs = 0.f, ldS = 0.f, lent = 0.f;
#pragma unroll
    for (int mi = 0; mi < 4; mi++) {
#pragma unroll
        for (int r = 0; r < 4; r++) {
            int node = nb + mi * 16 + quad * 4 + r;
            bool ok = node < NN;
            float logit = acc[mi][r] + myb;
            float mx = logit;
            for (int o = 1; o < 16; o <<= 1) mx = fmaxf(mx, __shfl_xor(mx, o, 16));
            float e = expf(logit - mx);
            float sum = e;
            for (int o = 1; o < 16; o <<= 1) sum += __shfl_xor(sum, o, 16);
            float a = e / sum;
            if (ok) {
                out_assign[(size_t)node * KK + l16] = a;
                out_f16[(size_t)node * KK + l16] = __float2half(a);
                lcs += a;
                ldS += degf[node] * a;
                lent += a * logf(a + 1e-8f);
            }
        }
    }
    // cs/dS: reduce across the 4 quads (same l16)
    lcs += __shfl_xor(lcs, 16); lcs += __shfl_xor(lcs, 32);
    ldS += __shfl_xor(ldS, 16); ldS += __shfl_xor(ldS, 32);
    for (int o = 32; o >= 1; o >>= 1) lent += __shfl_xor(lent, o);
    if (quad == 0) {
        atomicAdd(&scal[l16], lcs);
        atomicAdd(&scal[16 + l16], ldS);
    }
    if (lane == 0) atomicAdd(&scal[33], lent);
}

// ---------------- fused trace(S^T A S): 4 edges per thread, f16 assignments ----------------
__device__ inline float dot16h(const __half* a, const __half* b) {
    uint4 a0 = *(const uint4*)a, a1 = *(const uint4*)(a + 8);
    uint4 b0 = *(const uint4*)b, b1 = *(const uint4*)(b + 8);
    float p = 0.f;
    const __half2* xa = (const __half2*)&a0;
    const __half2* xb = (const __half2*)&b0;
#pragma unroll
    for (int i = 0; i < 4; i++) {
        float2 u = __half22float2(xa[i]), v = __half22float2(xb[i]);
        p += u.x * v.x + u.y * v.y;
    }
    xa = (const __half2*)&a1; xb = (const __half2*)&b1;
#pragma unroll
    for (int i = 0; i < 4; i++) {
        float2 u = __half22float2(xa[i]), v = __half22float2(xb[i]);
        p += u.x * v.x + u.y * v.y;
    }
    return p;
}

__global__ __launch_bounds__(256) void edge_trace(const int4* __restrict__ src4,
                                                  const int4* __restrict__ dst4,
                                                  const __half* __restrict__ Ah,
                                                  float* __restrict__ scal) {
    int e = blockIdx.x * blockDim.x + threadIdx.x;
    float p = 0.f;
    if (e < EE / 4) {
        int4 s = src4[e], d = dst4[e];
        p += dot16h(Ah + (size_t)s.x * KK, Ah + (size_t)d.x * KK);
        p += dot16h(Ah + (size_t)s.y * KK, Ah + (size_t)d.y * KK);
        p += dot16h(Ah + (size_t)s.z * KK, Ah + (size_t)d.z * KK);
        p += dot16h(Ah + (size_t)s.w * KK, Ah + (size_t)d.w * KK);
    }
    for (int o = 32; o >= 1; o >>= 1) p += __shfl_xor(p, o);
    __shared__ float sp;
    if (threadIdx.x == 0) sp = 0.f;
    __syncthreads();
    if ((threadIdx.x & 63) == 0) atomicAdd(&sp, p);
    __syncthreads();
    if (threadIdx.x == 0) atomicAdd(&scal[32], sp);
}

// ---------------- pooled partial: part[by][k][d] = sum_{n in chunk} a[n][k]*emb[n][d] ----------------
// ONE isolated change vs round 0: no atomics — each node-chunk writes its own
// 16x512 partial (coalesced), finalize does the 400-way reduction. Removes
// 3.3M same-cache-line f32 atomics (~6400 serialized adds per line).
#define PCH 125
__global__ __launch_bounds__(256) void pooled_partial(const float* __restrict__ emb,
                                                      const float* __restrict__ assign,
                                                      float* __restrict__ part) {
    int d = blockIdx.x * 256 + threadIdx.x;
    int c0 = blockIdx.y * PCH;
    float acc[KK];
#pragma unroll
    for (int k = 0; k < KK; k++) acc[k] = 0.f;
    __shared__ float sa[PCH * KK];  // 8 KB
    {
        const float4* srcv = (const float4*)(assign + (size_t)c0 * KK);
        float4* dstv = (float4*)sa;
        for (int i = threadIdx.x; i < PCH * KK / 4; i += 256) dstv[i] = srcv[i];
    }
    __syncthreads();
    for (int j = 0; j < PCH; j++) {
        float ev = emb[(size_t)(c0 + j) * DD + d];
#pragma unroll
        for (int k4 = 0; k4 < 4; k4++) {
            float4 s4 = *(const float4*)&sa[j * KK + k4 * 4];
            acc[k4 * 4 + 0] += s4.x * ev;
            acc[k4 * 4 + 1] += s4.y * ev;
            acc[k4 * 4 + 2] += s4.z * ev;
            acc[k4 * 4 + 3] += s4.w * ev;
        }
    }
    float* dst = part + (size_t)blockIdx.y * (KK * DD);
#pragma unroll
    for (int k = 0; k < KK; k++) dst[k * DD + d] = acc[k];
}

// ---------------- finalize: reduce pooled partials + normalize + scalar losses ----------------
__global__ void finalize(const float* __restrict__ part, const float* __restrict__ scal,
                         float* __restrict__ out) {
    int bx = blockIdx.x, t = threadIdx.x;
    if (bx < 32) {
        int i = bx * 256 + t;  // 0..8191
        float s0 = 0.f, s1 = 0.f, s2 = 0.f, s3 = 0.f;
        for (int p = 0; p < 400; p += 4) {
            s0 += part[(size_t)p * 8192 + i];
            s1 += part[(size_t)(p + 1) * 8192 + i];
            s2 += part[(size_t)(p + 2) * 8192 + i];
            s3 += part[(size_t)(p + 3) * 8192 + i];
        }
        int k = i >> 9;  // i / DD
        out[800000 + i] = (s0 + s1 + s2 + s3) / (scal[k] + 1e-8f);
    } else if (t == 0) {
        float cs2 = 0.f, ds2 = 0.f;
        for (int k = 0; k < KK; k++) {
            cs2 += scal[k] * scal[k];
            ds2 += scal[16 + k] * scal[16 + k];
        }
        float two_m = (float)EE;  // sum(degrees) == E, 2m == E
        float normalizer = ds2 / two_m;
        float trace = scal[32];
        float spectral = -(trace - (float)KK * normalizer) / two_m;
        float collapse = sqrtf(cs2) / (float)NN * 4.0f - 1.0f;  // sqrt(K)=4
        float entl = 0.1f * scal[33] / (float)NN;
        out[808192] = spectral;
        out[808193] = collapse;  // COLLAPSE_REG = 1.0
        out[808194] = spectral + collapse + entl;
        out[808195] = entl;
    }
}

extern "C" void kernel_launch(void* const* d_in, const int* in_sizes, int n_in,
                              void* d_out, int out_size, void* d_ws, size_t ws_size,
                              hipStream_t stream) {
    const float* emb = (const float*)d_in[0];
    const int* esrc  = (const int*)d_in[1];
    const int* edst  = (const int*)d_in[2];
    const float* W1  = (const float*)d_in[3];
    const float* b1  = (const float*)d_in[4];
    const float* W2  = (const float*)d_in[5];
    const float* b2  = (const float*)d_in[6];
    const float* Wa  = (const float*)d_in[7];
    const float* ba  = (const float*)d_in[8];
    float* out = (float*)d_out;

    // workspace layout (4B units unless noted) — total ~56 MB
    int* indeg      = (int*)d_ws;            // 50000
    int* outdeg     = indeg + 50000;         // 50000
    int* cur        = outdeg + 50000;        // 50000
    float* pool_acc = (float*)(cur + 50000); // 8192 (unused, kept for layout)
    float* scal     = pool_acc + 8192;       // 64
    int* part       = (int*)(scal + 64);     // 256 (scan partials)
    int* off        = part + 256;            // 50001 (+pad to 50004)
    int* nbr        = off + 50004;           // 800000
    float* dis      = (float*)(nbr + 800000);// 50000
    float* degf     = dis + 50000;           // 50000
    __half* Wt1     = (__half*)(degf + 50000);   // 256*512 f16
    __half* Wt2     = Wt1 + 256 * 512;           // 256*256 f16
    __half* WaT     = Wt2 + 256 * 256;           // 16*256 f16
    __half* T       = WaT + 16 * 256;            // 50000*256 f16 (25.6 MB)
    __half* Hb      = T + (size_t)NN * HH;       // 50000*256 f16 (25.6 MB)
    __half* Ah      = T;  // f16 assignments alias T (dead after agg2)
    float* pool_part = (float*)Hb;  // 400*8192 f32 = 13.1 MB, Hb dead after assign_mfma

    // zero the atomically-accumulated region: indeg/outdeg/cur/pool_acc/scal
    zero_kernel<<<dim3(619), 256, 0, stream>>>((int*)d_ws, 158256);
    count_kernel<<<dim3(782), 256, 0, stream>>>((const int4*)esrc, (const int4*)edst,
                                                indeg, outdeg);

    // CSR offsets: 3-phase scan (+ dis/degf in p1)
    scan_p1<<<dim3(NB_SCAN), 256, 0, stream>>>(indeg, part, NN, outdeg, dis, degf);
    scan_p2<<<dim3(1), 256, 0, stream>>>(part, NB_SCAN, off + NN);
    scan_p3<<<dim3(NB_SCAN), 256, 0, stream>>>(indeg, part, off, NN);
    scatter_kernel<<<dim3(782), 256, 0, stream>>>((const int4*)esrc, (const int4*)edst,
                                                  off, cur, nbr);

    // weights -> f16 transposed, IMMEDIATELY before gemm1 (keeps Wt1/Wt2 hot in L2)
    transpose_w<<<dim3(784), 256, 0, stream>>>(W1, Wt1, W2, Wt2, Wa, WaT);

    // conv1: T = emb @ W1 ; Hb = selu(Ahat*T + b1)
    mfma_gemm<float, DD><<<dim3(392, 2), 256, 0, stream>>>(emb, Wt1, T, NN);
    agg_selu<<<dim3(6250), 256, 0, stream>>>(T, dis, off, nbr, b1, nullptr, Hb);

    // conv2: T = Hb @ W2 ; Hb = selu(Ahat*T + b2) + Hb (skip, in place)
    mfma_gemm<__half, HH><<<dim3(392, 2), 256, 0, stream>>>(Hb, Wt2, T, NN);
    agg_selu<<<dim3(6250), 256, 0, stream>>>(T, dis, off, nbr, b2, Hb, Hb);

    // head: assignments -> d_out[0..800000) (+f16 copy), loss partials
    assign_mfma<<<dim3(196), 256, 0, stream>>>(Hb, WaT, ba, degf, out, Ah, scal);
    edge_trace<<<dim3(782), 256, 0, stream>>>((const int4*)esrc, (const int4*)edst, Ah, scal);
    pooled_partial<<<dim3(2, 400), 256, 0, stream>>>(emb, out, pool_part);
    finalize<<<dim3(33), 256, 0, stream>>>(pool_part, scal, out);
}

// Round 6
// 597.166 us; speedup vs baseline: 1.0128x; 1.0128x over previous
//
#include <hip/hip_runtime.h>
#include <hip/hip_fp16.h>
#include <math.h>

#define NN 50000
#define EE 800000
#define DD 512
#define HH 256
#define KK 16
#define NB_SCAN 196  // ceil(NN/256)

typedef _Float16 half8_t __attribute__((ext_vector_type(8)));
typedef float f32x4 __attribute__((ext_vector_type(4)));

// ---------------- utility ----------------
__global__ void zero_kernel(int* __restrict__ p, int n) {
    int i = blockIdx.x * blockDim.x + threadIdx.x;
    if (i < n) p[i] = 0;
}

__global__ void count_kernel(const int4* __restrict__ src4, const int4* __restrict__ dst4,
                             int* __restrict__ indeg, int* __restrict__ outdeg) {
    int e = blockIdx.x * blockDim.x + threadIdx.x;
    if (e < EE / 4) {
        int4 s = src4[e], d = dst4[e];
        atomicAdd(&outdeg[s.x], 1); atomicAdd(&outdeg[s.y], 1);
        atomicAdd(&outdeg[s.z], 1); atomicAdd(&outdeg[s.w], 1);
        atomicAdd(&indeg[d.x], 1);  atomicAdd(&indeg[d.y], 1);
        atomicAdd(&indeg[d.z], 1);  atomicAdd(&indeg[d.w], 1);
    }
}

// ---------------- 3-phase multi-block exclusive scan (+node_prep fused in p1) ----------------
__global__ void scan_p1(const int* __restrict__ in, int* __restrict__ part, int n,
                        const int* __restrict__ outdeg, float* __restrict__ dis,
                        float* __restrict__ degf) {
    __shared__ int tile[256];
    int t = threadIdx.x;
    int i = blockIdx.x * 256 + t;
    int v = (i < n) ? in[i] : 0;
    tile[t] = v;
    if (i < n) {
        dis[i]  = 1.0f / sqrtf(1.0f + (float)v);
        degf[i] = (float)outdeg[i];
    }
    __syncthreads();
    for (int o = 128; o > 0; o >>= 1) {
        if (t < o) tile[t] += tile[t + o];
        __syncthreads();
    }
    if (t == 0) part[blockIdx.x] = tile[0];
}

__global__ void scan_p2(int* __restrict__ part, int nb, int* __restrict__ off_end) {
    __shared__ int tile[256];
    int t = threadIdx.x;
    int v = (t < nb) ? part[t] : 0;
    tile[t] = v;
    __syncthreads();
    for (int o = 1; o < 256; o <<= 1) {
        int x = (t >= o) ? tile[t - o] : 0;
        __syncthreads();
        tile[t] += x;
        __syncthreads();
    }
    if (t < nb) part[t] = tile[t] - v;  // exclusive base per block
    if (t == 255) *off_end = tile[255];
}

__global__ void scan_p3(const int* __restrict__ in, const int* __restrict__ part,
                        int* __restrict__ out, int n) {
    __shared__ int tile[256];
    int t = threadIdx.x;
    int i = blockIdx.x * 256 + t;
    int v = (i < n) ? in[i] : 0;
    tile[t] = v;
    __syncthreads();
    for (int o = 1; o < 256; o <<= 1) {
        int x = (t >= o) ? tile[t - o] : 0;
        __syncthreads();
        tile[t] += x;
        __syncthreads();
    }
    if (i < n) out[i] = part[blockIdx.x] + tile[t] - v;
}

__global__ void scatter_kernel(const int4* __restrict__ src4, const int4* __restrict__ dst4,
                               const int* __restrict__ off, int* __restrict__ cur,
                               int* __restrict__ nbr) {
    int e = blockIdx.x * blockDim.x + threadIdx.x;
    if (e < EE / 4) {
        int4 s = src4[e], d = dst4[e];
        int p;
        p = atomicAdd(&cur[d.x], 1); nbr[off[d.x] + p] = s.x;
        p = atomicAdd(&cur[d.y], 1); nbr[off[d.y] + p] = s.y;
        p = atomicAdd(&cur[d.z], 1); nbr[off[d.z] + p] = s.z;
        p = atomicAdd(&cur[d.w], 1); nbr[off[d.w] + p] = s.w;
    }
}

// ---------------- fused weight transpose + f16 convert (W1, W2, Wa) ----------------
// MUST stay a separate kernel immediately before gemm1: the latency-bound GEMM
// depends on Wt1/Wt2 being hot in L2 (r4: moving it 5 kernels earlier cost ~15 us;
// heavy traffic between it and gemm1 evicts the 384 KB of Wt).
__global__ void transpose_w(const float* __restrict__ W1, __half* __restrict__ Wt1,
                            const float* __restrict__ W2, __half* __restrict__ Wt2,
                            const float* __restrict__ Wa, __half* __restrict__ WaT) {
    int i = blockIdx.x * 256 + threadIdx.x;
    if (i < DD * HH) {
        int k = i / HH, n = i % HH;
        Wt1[(size_t)n * DD + k] = __float2half(W1[i]);
    } else if (i < DD * HH + HH * HH) {
        int j = i - DD * HH;
        int k = j / HH, n = j % HH;
        Wt2[(size_t)n * HH + k] = __float2half(W2[j]);
    } else if (i < DD * HH + HH * HH + HH * KK) {
        int j = i - DD * HH - HH * HH;
        int k = j / KK, n = j % KK;
        WaT[n * HH + k] = __float2half(Wa[j]);
    }
}

// ---------------- MFMA f16 GEMM: C[M,256] = A[M,KDIM] @ Wt[256,KDIM]^T ----------------
template <typename TA, int KDIM>
__global__ __launch_bounds__(256) void mfma_gemm(const TA* __restrict__ A,
                                                 const __half* __restrict__ Bt,
                                                 __half* __restrict__ C, int M) {
    constexpr bool F32 = sizeof(TA) == 4;
    constexpr int SROW = F32 ? 36 : 40;  // LDS row stride: 2-way bank alias max
    constexpr int EPG  = F32 ? 4 : 8;    // elements per 16B granule
    constexpr int GPR  = 32 / EPG;       // granules per k-row of 32
    constexpr int RPP  = 256 / GPR;      // rows staged per pass
    constexpr int NP   = 128 / RPP;      // staging passes
    constexpr int KI   = KDIM / 32;

    __shared__ TA As[2][128 * SROW];

    int t = threadIdx.x;
    int wave = t >> 6, lane = t & 63, quad = lane >> 4, l16 = lane & 15;
    int row0 = blockIdx.x * 128, col0 = blockIdx.y * 128;
    int wm = (wave & 1) * 64, wn = (wave >> 1) * 64;
    int srow = t / GPR, sg = t % GPR;

    f32x4 acc[4][4] = {};
    uint4 sreg[NP];
    uint4 bcur[4];

    const __half* brow[4];
#pragma unroll
    for (int ni = 0; ni < 4; ni++)
        brow[ni] = Bt + (size_t)(col0 + wn + ni * 16 + l16) * KDIM + quad * 8;

    auto gloadA = [&](int k0) {
#pragma unroll
        for (int p = 0; p < NP; p++) {
            int gr = row0 + p * RPP + srow;
            if (gr < M)
                sreg[p] = *(const uint4*)(A + (size_t)gr * KDIM + k0 + sg * EPG);
            else
                sreg[p] = make_uint4(0, 0, 0, 0);
        }
    };
    auto sstore = [&](int buf) {
#pragma unroll
        for (int p = 0; p < NP; p++)
            *(uint4*)&As[buf][(p * RPP + srow) * SROW + sg * EPG] = sreg[p];
    };

    gloadA(0);
#pragma unroll
    for (int ni = 0; ni < 4; ni++) bcur[ni] = *(const uint4*)(brow[ni]);
    sstore(0);
    __syncthreads();

#pragma unroll
    for (int i = 0; i < KI; i++) {
        int cur = i & 1;
        uint4 bnext[4];
        if (i + 1 < KI) {
            gloadA((i + 1) * 32);
#pragma unroll
            for (int ni = 0; ni < 4; ni++)
                bnext[ni] = *(const uint4*)(brow[ni] + (i + 1) * 32);
        }

        half8_t af[4];
#pragma unroll
        for (int mi = 0; mi < 4; mi++) {
            int row = wm + mi * 16 + l16;
            if constexpr (F32) {
                const float* pl = (const float*)&As[cur][0] + row * SROW + quad * 8;
                float4 x0 = *(const float4*)pl;
                float4 x1 = *(const float4*)(pl + 4);
                half8_t h;
                h[0] = (_Float16)x0.x; h[1] = (_Float16)x0.y;
                h[2] = (_Float16)x0.z; h[3] = (_Float16)x0.w;
                h[4] = (_Float16)x1.x; h[5] = (_Float16)x1.y;
                h[6] = (_Float16)x1.z; h[7] = (_Float16)x1.w;
                af[mi] = h;
            } else {
                af[mi] = *(const half8_t*)&As[cur][row * SROW + quad * 8];
            }
        }
#pragma unroll
        for (int mi = 0; mi < 4; mi++)
#pragma unroll
            for (int ni = 0; ni < 4; ni++)
                acc[mi][ni] = __builtin_amdgcn_mfma_f32_16x16x32_f16(
                    af[mi], *(half8_t*)&bcur[ni], acc[mi][ni], 0, 0, 0);

        if (i + 1 < KI) {
            sstore(cur ^ 1);
#pragma unroll
            for (int ni = 0; ni < 4; ni++) bcur[ni] = bnext[ni];
        }
        __syncthreads();
    }

#pragma unroll
    for (int mi = 0; mi < 4; mi++) {
#pragma unroll
        for (int r = 0; r < 4; r++) {
            int rr = row0 + wm + mi * 16 + quad * 4 + r;
            if (rr < M) {
#pragma unroll
                for (int ni = 0; ni < 4; ni++) {
                    C[(size_t)rr * HH + col0 + wn + ni * 16 + l16] =
                        __float2half(acc[mi][ni][r]);
                }
            }
        }
    }
}

// ---------------- aggregation + bias + SELU (+optional skip) ----------------
__device__ inline void fma8(float* acc, uint4 raw, float w) {
    const __half2* h = (const __half2*)&raw;
#pragma unroll
    for (int i = 0; i < 4; i++) {
        float2 f = __half22float2(h[i]);
        acc[2 * i]     += w * f.x;
        acc[2 * i + 1] += w * f.y;
    }
}

__global__ __launch_bounds__(256) void agg_selu(const __half* __restrict__ T,
                                                const float* __restrict__ dis,
                                                const int* __restrict__ off,
                                                const int* __restrict__ nbr,
                                                const float* __restrict__ bias,
                                                const __half* skip, __half* out) {
    int t = threadIdx.x;
    int l32 = t & 31;
    int n = blockIdx.x * 8 + (t >> 5);
    int c = l32 * 8;
    float dn = dis[n];

    float acc[8];
#pragma unroll
    for (int i = 0; i < 8; i++) acc[i] = 0.f;
    fma8(acc, *(const uint4*)(T + (size_t)n * HH + c), dn * dn);  // self-loop

    int s0 = off[n], s1 = off[n + 1];
    for (int base = s0; base < s1; base += 32) {
        int cnt = min(32, s1 - base);
        int sidv = 0; float sdsv = 0.f;
        if (l32 < cnt) {
            sidv = nbr[base + l32];
            sdsv = dis[sidv] * dn;
        }
        int j = 0;
        for (; j + 8 <= cnt; j += 8) {
            int a0 = __shfl(sidv, j, 32),     a1 = __shfl(sidv, j + 1, 32);
            int a2 = __shfl(sidv, j + 2, 32), a3 = __shfl(sidv, j + 3, 32);
            int a4 = __shfl(sidv, j + 4, 32), a5 = __shfl(sidv, j + 5, 32);
            int a6 = __shfl(sidv, j + 6, 32), a7 = __shfl(sidv, j + 7, 32);
            float w0 = __shfl(sdsv, j, 32),     w1 = __shfl(sdsv, j + 1, 32);
            float w2 = __shfl(sdsv, j + 2, 32), w3 = __shfl(sdsv, j + 3, 32);
            float w4 = __shfl(sdsv, j + 4, 32), w5 = __shfl(sdsv, j + 5, 32);
            float w6 = __shfl(sdsv, j + 6, 32), w7 = __shfl(sdsv, j + 7, 32);
            uint4 r0 = *(const uint4*)(T + (size_t)a0 * HH + c);
            uint4 r1 = *(const uint4*)(T + (size_t)a1 * HH + c);
            uint4 r2 = *(const uint4*)(T + (size_t)a2 * HH + c);
            uint4 r3 = *(const uint4*)(T + (size_t)a3 * HH + c);
            uint4 r4 = *(const uint4*)(T + (size_t)a4 * HH + c);
            uint4 r5 = *(const uint4*)(T + (size_t)a5 * HH + c);
            uint4 r6 = *(const uint4*)(T + (size_t)a6 * HH + c);
            uint4 r7 = *(const uint4*)(T + (size_t)a7 * HH + c);
            fma8(acc, r0, w0); fma8(acc, r1, w1);
            fma8(acc, r2, w2); fma8(acc, r3, w3);
            fma8(acc, r4, w4); fma8(acc, r5, w5);
            fma8(acc, r6, w6); fma8(acc, r7, w7);
        }
        for (; j < cnt; j++) {
            int s = __shfl(sidv, j, 32);
            float w = __shfl(sdsv, j, 32);
            fma8(acc, *(const uint4*)(T + (size_t)s * HH + c), w);
        }
    }

    const float scale = 1.0507009873554805f;
    const float alpha = 1.6732632423543772f;
    float4 b0 = *(const float4*)(bias + c);
    float4 b1 = *(const float4*)(bias + c + 4);
    float bb[8] = {b0.x, b0.y, b0.z, b0.w, b1.x, b1.y, b1.z, b1.w};
    float sk8[8];
#pragma unroll
    for (int i = 0; i < 8; i++) sk8[i] = 0.f;
    if (skip) {
        uint4 raw = *(const uint4*)(skip + (size_t)n * HH + c);
        const __half2* h = (const __half2*)&raw;
#pragma unroll
        for (int i = 0; i < 4; i++) {
            float2 f = __half22float2(h[i]);
            sk8[2 * i] = f.x; sk8[2 * i + 1] = f.y;
        }
    }
    _Float16 res[8];
#pragma unroll
    for (int i = 0; i < 8; i++) {
        float v = acc[i] + bb[i];
        float r = v > 0.f ? scale * v : scale * alpha * expm1f(v);
        res[i] = (_Float16)(r + sk8[i]);
    }
    *(uint4*)(out + (size_t)n * HH + c) = *(uint4*)res;
}

// ---------------- assignment head via MFMA ----------------
// Wave = 64 nodes; logits = Hb[64x256] @ WaT[16x256]^T via 4 mfma per K-step.
__global__ __launch_bounds__(256) void assign_mfma(const __half* __restrict__ Hb,
                                                   const __half* __restrict__ WaT,
                                                   const float* __restrict__ ba,
                                                   const float* __restrict__ degf,
                                                   float* __restrict__ out_assign,
                                                   __half* __restrict__ out_f16,
                                                   float* __restrict__ scal) {
    int t = threadIdx.x;
    int wave = t >> 6, lane = t & 63, quad = lane >> 4, l16 = lane & 15;
    int nb = blockIdx.x * 256 + wave * 64;

    f32x4 acc[4] = {};
    const __half* bp = WaT + l16 * HH + quad * 8;
    const __half* ap[4];
#pragma unroll
    for (int mi = 0; mi < 4; mi++) {
        int r = nb + mi * 16 + l16;
        if (r >= NN) r = NN - 1;
        ap[mi] = Hb + (size_t)r * HH + quad * 8;
    }
#pragma unroll
    for (int s = 0; s < 8; s++) {
        half8_t bf = *(const half8_t*)(bp + s * 32);
#pragma unroll
        for (int mi = 0; mi < 4; mi++) {
            half8_t af = *(const half8_t*)(ap[mi] + s * 32);
            acc[mi] = __builtin_amdgcn_mfma_f32_16x16x32_f16(af, bf, acc[mi], 0, 0, 0);
        }
    }

    float myb = ba[l16];
    float lcs = 0.f, ldS = 0.f, lent = 0.f;
#pragma unroll
    for (int mi = 0; mi < 4; mi++) {
#pragma unroll
        for (int r = 0; r < 4; r++) {
            int node = nb + mi * 16 + quad * 4 + r;
            bool ok = node < NN;
            float logit = acc[mi][r] + myb;
            float mx = logit;
            for (int o = 1; o < 16; o <<= 1) mx = fmaxf(mx, __shfl_xor(mx, o, 16));
            float e = expf(logit - mx);
            float sum = e;
            for (int o = 1; o < 16; o <<= 1) sum += __shfl_xor(sum, o, 16);
            float a = e / sum;
            if (ok) {
                out_assign[(size_t)node * KK + l16] = a;
                out_f16[(size_t)node * KK + l16] = __float2half(a);
                lcs += a;
                ldS += degf[node] * a;
                lent += a * logf(a + 1e-8f);
            }
        }
    }
    // cs/dS: reduce across the 4 quads (same l16)
    lcs += __shfl_xor(lcs, 16); lcs += __shfl_xor(lcs, 32);
    ldS += __shfl_xor(ldS, 16); ldS += __shfl_xor(ldS, 32);
    for (int o = 32; o >= 1; o >>= 1) lent += __shfl_xor(lent, o);
    if (quad == 0) {
        atomicAdd(&scal[l16], lcs);
        atomicAdd(&scal[16 + l16], ldS);
    }
    if (lane == 0) atomicAdd(&scal[33], lent);
}

// ---------------- fused tail: edge_trace (blocks 0..781) + pooled partial (blocks 782..1581) ----
// The two are data-independent; trace is L2-gather/VALU-bound, pooled is HBM-stream-bound.
// One launch lets them overlap instead of serializing on the stream.
__device__ inline float dot16h(const __half* a, const __half* b) {
    uint4 a0 = *(const uint4*)a, a1 = *(const uint4*)(a + 8);
    uint4 b0 = *(const uint4*)b, b1 = *(const uint4*)(b + 8);
    float p = 0.f;
    const __half2* xa = (const __half2*)&a0;
    const __half2* xb = (const __half2*)&b0;
#pragma unroll
    for (int i = 0; i < 4; i++) {
        float2 u = __half22float2(xa[i]), v = __half22float2(xb[i]);
        p += u.x * v.x + u.y * v.y;
    }
    xa = (const __half2*)&a1; xb = (const __half2*)&b1;
#pragma unroll
    for (int i = 0; i < 4; i++) {
        float2 u = __half22float2(xa[i]), v = __half22float2(xb[i]);
        p += u.x * v.x + u.y * v.y;
    }
    return p;
}

#define PCH 125
__global__ __launch_bounds__(256) void trace_pooled(const int4* __restrict__ src4,
                                                    const int4* __restrict__ dst4,
                                                    const __half* __restrict__ Ah,
                                                    float* __restrict__ scal,
                                                    const float* __restrict__ emb,
                                                    const float* __restrict__ assign,
                                                    float* __restrict__ part) {
    __shared__ float sa[PCH * KK];  // 8 KB; sa[0] doubles as the trace scratch
    int bx = blockIdx.x, t = threadIdx.x;
    if (bx < 782) {
        // ---- edge_trace role ----
        int e = bx * 256 + t;
        float p = 0.f;
        if (e < EE / 4) {
            int4 s = src4[e], d = dst4[e];
            p += dot16h(Ah + (size_t)s.x * KK, Ah + (size_t)d.x * KK);
            p += dot16h(Ah + (size_t)s.y * KK, Ah + (size_t)d.y * KK);
            p += dot16h(Ah + (size_t)s.z * KK, Ah + (size_t)d.z * KK);
            p += dot16h(Ah + (size_t)s.w * KK, Ah + (size_t)d.w * KK);
        }
        for (int o = 32; o >= 1; o >>= 1) p += __shfl_xor(p, o);
        if (t == 0) sa[0] = 0.f;
        __syncthreads();
        if ((t & 63) == 0) atomicAdd(&sa[0], p);
        __syncthreads();
        if (t == 0) atomicAdd(&scal[32], sa[0]);
    } else {
        // ---- pooled partial role: part[by][k][d] = sum_{n in chunk} a[n][k]*emb[n][d] ----
        int j = bx - 782;
        int d = (j & 1) * 256 + t;
        int by = j >> 1;
        int c0 = by * PCH;
        float acc[KK];
#pragma unroll
        for (int k = 0; k < KK; k++) acc[k] = 0.f;
        {
            const float4* srcv = (const float4*)(assign + (size_t)c0 * KK);
            float4* dstv = (float4*)sa;
            for (int i = t; i < PCH * KK / 4; i += 256) dstv[i] = srcv[i];
        }
        __syncthreads();
        for (int jj = 0; jj < PCH; jj++) {
            float ev = emb[(size_t)(c0 + jj) * DD + d];
#pragma unroll
            for (int k4 = 0; k4 < 4; k4++) {
                float4 s4 = *(const float4*)&sa[jj * KK + k4 * 4];
                acc[k4 * 4 + 0] += s4.x * ev;
                acc[k4 * 4 + 1] += s4.y * ev;
                acc[k4 * 4 + 2] += s4.z * ev;
                acc[k4 * 4 + 3] += s4.w * ev;
            }
        }
        float* dst = part + (size_t)by * (KK * DD);
#pragma unroll
        for (int k = 0; k < KK; k++) dst[k * DD + d] = acc[k];
    }
}

// ---------------- finalize: reduce pooled partials + normalize + scalar losses ----------------
__global__ void finalize(const float* __restrict__ part, const float* __restrict__ scal,
                         float* __restrict__ out) {
    int bx = blockIdx.x, t = threadIdx.x;
    if (bx < 32) {
        int i = bx * 256 + t;  // 0..8191
        float s0 = 0.f, s1 = 0.f, s2 = 0.f, s3 = 0.f;
        for (int p = 0; p < 400; p += 4) {
            s0 += part[(size_t)p * 8192 + i];
            s1 += part[(size_t)(p + 1) * 8192 + i];
            s2 += part[(size_t)(p + 2) * 8192 + i];
            s3 += part[(size_t)(p + 3) * 8192 + i];
        }
        int k = i >> 9;  // i / DD
        out[800000 + i] = (s0 + s1 + s2 + s3) / (scal[k] + 1e-8f);
    } else if (t == 0) {
        float cs2 = 0.f, ds2 = 0.f;
        for (int k = 0; k < KK; k++) {
            cs2 += scal[k] * scal[k];
            ds2 += scal[16 + k] * scal[16 + k];
        }
        float two_m = (float)EE;  // sum(degrees) == E, 2m == E
        float normalizer = ds2 / two_m;
        float trace = scal[32];
        float spectral = -(trace - (float)KK * normalizer) / two_m;
        float collapse = sqrtf(cs2) / (float)NN * 4.0f - 1.0f;  // sqrt(K)=4
        float entl = 0.1f * scal[33] / (float)NN;
        out[808192] = spectral;
        out[808193] = collapse;  // COLLAPSE_REG = 1.0
        out[808194] = spectral + collapse + entl;
        out[808195] = entl;
    }
}

extern "C" void kernel_launch(void* const* d_in, const int* in_sizes, int n_in,
                              void* d_out, int out_size, void* d_ws, size_t ws_size,
                              hipStream_t stream) {
    const float* emb = (const float*)d_in[0];
    const int* esrc  = (const int*)d_in[1];
    const int* edst  = (const int*)d_in[2];
    const float* W1  = (const float*)d_in[3];
    const float* b1  = (const float*)d_in[4];
    const float* W2  = (const float*)d_in[5];
    const float* b2  = (const float*)d_in[6];
    const float* Wa  = (const float*)d_in[7];
    const float* ba  = (const float*)d_in[8];
    float* out = (float*)d_out;

    // workspace layout (4B units unless noted) — total ~56 MB
    int* indeg      = (int*)d_ws;            // 50000
    int* outdeg     = indeg + 50000;         // 50000
    int* cur        = outdeg + 50000;        // 50000
    float* pool_acc = (float*)(cur + 50000); // 8192 (unused, kept for layout)
    float* scal     = pool_acc + 8192;       // 64
    int* part       = (int*)(scal + 64);     // 256 (scan partials)
    int* off        = part + 256;            // 50001 (+pad to 50004)
    int* nbr        = off + 50004;           // 800000
    float* dis      = (float*)(nbr + 800000);// 50000
    float* degf     = dis + 50000;           // 50000
    __half* Wt1     = (__half*)(degf + 50000);   // 256*512 f16
    __half* Wt2     = Wt1 + 256 * 512;           // 256*256 f16
    __half* WaT     = Wt2 + 256 * 256;           // 16*256 f16
    __half* T       = WaT + 16 * 256;            // 50000*256 f16 (25.6 MB)
    __half* Hb      = T + (size_t)NN * HH;       // 50000*256 f16 (25.6 MB)
    __half* Ah      = T;  // f16 assignments alias T (dead after agg2)
    float* pool_part = (float*)Hb;  // 400*8192 f32 = 13.1 MB, Hb dead after assign_mfma

    // zero the atomically-accumulated region: indeg/outdeg/cur/pool_acc/scal
    zero_kernel<<<dim3(619), 256, 0, stream>>>((int*)d_ws, 158256);
    count_kernel<<<dim3(782), 256, 0, stream>>>((const int4*)esrc, (const int4*)edst,
                                                indeg, outdeg);

    // CSR offsets: 3-phase scan (+ dis/degf in p1)
    scan_p1<<<dim3(NB_SCAN), 256, 0, stream>>>(indeg, part, NN, outdeg, dis, degf);
    scan_p2<<<dim3(1), 256, 0, stream>>>(part, NB_SCAN, off + NN);
    scan_p3<<<dim3(NB_SCAN), 256, 0, stream>>>(indeg, part, off, NN);
    scatter_kernel<<<dim3(782), 256, 0, stream>>>((const int4*)esrc, (const int4*)edst,
                                                  off, cur, nbr);

    // weights -> f16 transposed, IMMEDIATELY before gemm1 (keeps Wt1/Wt2 hot in L2)
    transpose_w<<<dim3(784), 256, 0, stream>>>(W1, Wt1, W2, Wt2, Wa, WaT);

    // conv1: T = emb @ W1 ; Hb = selu(Ahat*T + b1)
    mfma_gemm<float, DD><<<dim3(392, 2), 256, 0, stream>>>(emb, Wt1, T, NN);
    agg_selu<<<dim3(6250), 256, 0, stream>>>(T, dis, off, nbr, b1, nullptr, Hb);

    // conv2: T = Hb @ W2 ; Hb = selu(Ahat*T + b2) + Hb (skip, in place)
    mfma_gemm<__half, HH><<<dim3(392, 2), 256, 0, stream>>>(Hb, Wt2, T, NN);
    agg_selu<<<dim3(6250), 256, 0, stream>>>(T, dis, off, nbr, b2, Hb, Hb);

    // head: assignments -> d_out[0..800000) (+f16 copy), loss partials
    assign_mfma<<<dim3(196), 256, 0, stream>>>(Hb, WaT, ba, degf, out, Ah, scal);
    // fused tail: trace (782 blocks) overlapped with pooled partials (800 blocks)
    trace_pooled<<<dim3(1582), 256, 0, stream>>>((const int4*)esrc, (const int4*)edst,
                                                 Ah, scal, emb, out, pool_part);
    finalize<<<dim3(33), 256, 0, stream>>>(pool_part, scal, out);
}

// Round 7
// 576.871 us; speedup vs baseline: 1.0485x; 1.0352x over previous
//
#include <hip/hip_runtime.h>
#include <hip/hip_fp16.h>
#include <math.h>

#define NN 50000
#define EE 800000
#define DD 512
#define HH 256
#define KK 16
#define NB_SCAN 196  // ceil(NN/256)

typedef _Float16 half8_t __attribute__((ext_vector_type(8)));
typedef float f32x4 __attribute__((ext_vector_type(4)));

// ---------------- utility ----------------
__global__ void zero_kernel(int* __restrict__ p, int n) {
    int i = blockIdx.x * blockDim.x + threadIdx.x;
    if (i < n) p[i] = 0;
}

__global__ void count_kernel(const int4* __restrict__ src4, const int4* __restrict__ dst4,
                             int* __restrict__ indeg, int* __restrict__ outdeg) {
    int e = blockIdx.x * blockDim.x + threadIdx.x;
    if (e < EE / 4) {
        int4 s = src4[e], d = dst4[e];
        atomicAdd(&outdeg[s.x], 1); atomicAdd(&outdeg[s.y], 1);
        atomicAdd(&outdeg[s.z], 1); atomicAdd(&outdeg[s.w], 1);
        atomicAdd(&indeg[d.x], 1);  atomicAdd(&indeg[d.y], 1);
        atomicAdd(&indeg[d.z], 1);  atomicAdd(&indeg[d.w], 1);
    }
}

// ---------------- 3-phase multi-block exclusive scan (+node_prep fused in p1) ----------------
__global__ void scan_p1(const int* __restrict__ in, int* __restrict__ part, int n,
                        const int* __restrict__ outdeg, float* __restrict__ dis,
                        float* __restrict__ degf) {
    __shared__ int tile[256];
    int t = threadIdx.x;
    int i = blockIdx.x * 256 + t;
    int v = (i < n) ? in[i] : 0;
    tile[t] = v;
    if (i < n) {
        dis[i]  = 1.0f / sqrtf(1.0f + (float)v);
        degf[i] = (float)outdeg[i];
    }
    __syncthreads();
    for (int o = 128; o > 0; o >>= 1) {
        if (t < o) tile[t] += tile[t + o];
        __syncthreads();
    }
    if (t == 0) part[blockIdx.x] = tile[0];
}

__global__ void scan_p2(int* __restrict__ part, int nb, int* __restrict__ off_end) {
    __shared__ int tile[256];
    int t = threadIdx.x;
    int v = (t < nb) ? part[t] : 0;
    tile[t] = v;
    __syncthreads();
    for (int o = 1; o < 256; o <<= 1) {
        int x = (t >= o) ? tile[t - o] : 0;
        __syncthreads();
        tile[t] += x;
        __syncthreads();
    }
    if (t < nb) part[t] = tile[t] - v;  // exclusive base per block
    if (t == 255) *off_end = tile[255];
}

__global__ void scan_p3(const int* __restrict__ in, const int* __restrict__ part,
                        int* __restrict__ out, int n) {
    __shared__ int tile[256];
    int t = threadIdx.x;
    int i = blockIdx.x * 256 + t;
    int v = (i < n) ? in[i] : 0;
    tile[t] = v;
    __syncthreads();
    for (int o = 1; o < 256; o <<= 1) {
        int x = (t >= o) ? tile[t - o] : 0;
        __syncthreads();
        tile[t] += x;
        __syncthreads();
    }
    if (i < n) out[i] = part[blockIdx.x] + tile[t] - v;
}

// ---------------- fused weight transpose + f16 convert (W1, W2, Wa) ----------------
// MUST stay a separate kernel immediately before gemm1: the latency-bound GEMM
// depends on Wt1/Wt2 being hot in L2 (r4: moving it earlier cost ~15 us).
__global__ void transpose_w(const float* __restrict__ W1, __half* __restrict__ Wt1,
                            const float* __restrict__ W2, __half* __restrict__ Wt2,
                            const float* __restrict__ Wa, __half* __restrict__ WaT) {
    int i = blockIdx.x * 256 + threadIdx.x;
    if (i < DD * HH) {
        int k = i / HH, n = i % HH;
        Wt1[(size_t)n * DD + k] = __float2half(W1[i]);
    } else if (i < DD * HH + HH * HH) {
        int j = i - DD * HH;
        int k = j / HH, n = j % HH;
        Wt2[(size_t)n * HH + k] = __float2half(W2[j]);
    } else if (i < DD * HH + HH * HH + HH * KK) {
        int j = i - DD * HH - HH * HH;
        int k = j / KK, n = j % KK;
        WaT[n * HH + k] = __float2half(Wa[j]);
    }
}

// ---------------- fused gemm1 (blocks 0..783) + CSR scatter (blocks 784..1565) ----------------
// gemm1 is latency-bound at ~18% occupancy (all pipes <8%); scatter's atomic/
// random-write waves fill its idle issue slots. Deps: scatter needs off/cur
// (scans done); agg1 needs both outputs; fused kernel completes when all blocks do.
// Gemm blocks take indices [0,784) so they dispatch first.
__global__ __launch_bounds__(256) void gemm1_scatter(
        const float* __restrict__ A, const __half* __restrict__ Bt,
        __half* __restrict__ C, int M,
        const int4* __restrict__ src4, const int4* __restrict__ dst4,
        const int* __restrict__ off, int* __restrict__ cur, int* __restrict__ nbr) {
    constexpr int SROW = 36;   // f32 LDS row stride
    constexpr int EPG  = 4;    // f32 elems per 16B granule
    constexpr int GPR  = 8;    // granules per 32-elem k-row
    constexpr int RPP  = 32;   // rows per staging pass
    constexpr int NP   = 4;    // staging passes
    constexpr int KI   = DD / 32;

    __shared__ float As[2][128 * SROW];  // 36 KB (reserved by scatter blocks too; harmless)

    int b = blockIdx.x;
    int t = threadIdx.x;
    if (b >= 784) {
        // ---- scatter role ----
        int e = (b - 784) * 256 + t;
        if (e < EE / 4) {
            int4 s = src4[e], d = dst4[e];
            int p;
            p = atomicAdd(&cur[d.x], 1); nbr[off[d.x] + p] = s.x;
            p = atomicAdd(&cur[d.y], 1); nbr[off[d.y] + p] = s.y;
            p = atomicAdd(&cur[d.z], 1); nbr[off[d.z] + p] = s.z;
            p = atomicAdd(&cur[d.w], 1); nbr[off[d.w] + p] = s.w;
        }
        return;
    }

    // ---- gemm role: row0 from b>>1, col half from b&1 (adjacent blocks share A panel) ----
    int wave = t >> 6, lane = t & 63, quad = lane >> 4, l16 = lane & 15;
    int row0 = (b >> 1) * 128, col0 = (b & 1) * 128;
    int wm = (wave & 1) * 64, wn = (wave >> 1) * 64;
    int srow = t / GPR, sg = t % GPR;

    f32x4 acc[4][4] = {};
    uint4 sreg[NP];
    uint4 bcur[4];

    const __half* brow[4];
#pragma unroll
    for (int ni = 0; ni < 4; ni++)
        brow[ni] = Bt + (size_t)(col0 + wn + ni * 16 + l16) * DD + quad * 8;

    auto gloadA = [&](int k0) {
#pragma unroll
        for (int p = 0; p < NP; p++) {
            int gr = row0 + p * RPP + srow;
            if (gr < M)
                sreg[p] = *(const uint4*)(A + (size_t)gr * DD + k0 + sg * EPG);
            else
                sreg[p] = make_uint4(0, 0, 0, 0);
        }
    };
    auto sstore = [&](int buf) {
#pragma unroll
        for (int p = 0; p < NP; p++)
            *(uint4*)&As[buf][(p * RPP + srow) * SROW + sg * EPG] = sreg[p];
    };

    gloadA(0);
#pragma unroll
    for (int ni = 0; ni < 4; ni++) bcur[ni] = *(const uint4*)(brow[ni]);
    sstore(0);
    __syncthreads();

#pragma unroll
    for (int i = 0; i < KI; i++) {
        int cur_b = i & 1;
        uint4 bnext[4];
        if (i + 1 < KI) {
            gloadA((i + 1) * 32);
#pragma unroll
            for (int ni = 0; ni < 4; ni++)
                bnext[ni] = *(const uint4*)(brow[ni] + (i + 1) * 32);
        }

        half8_t af[4];
#pragma unroll
        for (int mi = 0; mi < 4; mi++) {
            int row = wm + mi * 16 + l16;
            const float* pl = &As[cur_b][0] + row * SROW + quad * 8;
            float4 x0 = *(const float4*)pl;
            float4 x1 = *(const float4*)(pl + 4);
            half8_t h;
            h[0] = (_Float16)x0.x; h[1] = (_Float16)x0.y;
            h[2] = (_Float16)x0.z; h[3] = (_Float16)x0.w;
            h[4] = (_Float16)x1.x; h[5] = (_Float16)x1.y;
            h[6] = (_Float16)x1.z; h[7] = (_Float16)x1.w;
            af[mi] = h;
        }
#pragma unroll
        for (int mi = 0; mi < 4; mi++)
#pragma unroll
            for (int ni = 0; ni < 4; ni++)
                acc[mi][ni] = __builtin_amdgcn_mfma_f32_16x16x32_f16(
                    af[mi], *(half8_t*)&bcur[ni], acc[mi][ni], 0, 0, 0);

        if (i + 1 < KI) {
            sstore(cur_b ^ 1);
#pragma unroll
            for (int ni = 0; ni < 4; ni++) bcur[ni] = bnext[ni];
        }
        __syncthreads();
    }

#pragma unroll
    for (int mi = 0; mi < 4; mi++) {
#pragma unroll
        for (int r = 0; r < 4; r++) {
            int rr = row0 + wm + mi * 16 + quad * 4 + r;
            if (rr < M) {
#pragma unroll
                for (int ni = 0; ni < 4; ni++) {
                    C[(size_t)rr * HH + col0 + wn + ni * 16 + l16] =
                        __float2half(acc[mi][ni][r]);
                }
            }
        }
    }
}

// ---------------- MFMA f16 GEMM (gemm2): C[M,256] = A[M,KDIM] @ Wt[256,KDIM]^T ----------------
template <typename TA, int KDIM>
__global__ __launch_bounds__(256) void mfma_gemm(const TA* __restrict__ A,
                                                 const __half* __restrict__ Bt,
                                                 __half* __restrict__ C, int M) {
    constexpr bool F32 = sizeof(TA) == 4;
    constexpr int SROW = F32 ? 36 : 40;  // LDS row stride: 2-way bank alias max
    constexpr int EPG  = F32 ? 4 : 8;    // elements per 16B granule
    constexpr int GPR  = 32 / EPG;       // granules per k-row of 32
    constexpr int RPP  = 256 / GPR;      // rows staged per pass
    constexpr int NP   = 128 / RPP;      // staging passes
    constexpr int KI   = KDIM / 32;

    __shared__ TA As[2][128 * SROW];

    int t = threadIdx.x;
    int wave = t >> 6, lane = t & 63, quad = lane >> 4, l16 = lane & 15;
    int row0 = blockIdx.x * 128, col0 = blockIdx.y * 128;
    int wm = (wave & 1) * 64, wn = (wave >> 1) * 64;
    int srow = t / GPR, sg = t % GPR;

    f32x4 acc[4][4] = {};
    uint4 sreg[NP];
    uint4 bcur[4];

    const __half* brow[4];
#pragma unroll
    for (int ni = 0; ni < 4; ni++)
        brow[ni] = Bt + (size_t)(col0 + wn + ni * 16 + l16) * KDIM + quad * 8;

    auto gloadA = [&](int k0) {
#pragma unroll
        for (int p = 0; p < NP; p++) {
            int gr = row0 + p * RPP + srow;
            if (gr < M)
                sreg[p] = *(const uint4*)(A + (size_t)gr * KDIM + k0 + sg * EPG);
            else
                sreg[p] = make_uint4(0, 0, 0, 0);
        }
    };
    auto sstore = [&](int buf) {
#pragma unroll
        for (int p = 0; p < NP; p++)
            *(uint4*)&As[buf][(p * RPP + srow) * SROW + sg * EPG] = sreg[p];
    };

    gloadA(0);
#pragma unroll
    for (int ni = 0; ni < 4; ni++) bcur[ni] = *(const uint4*)(brow[ni]);
    sstore(0);
    __syncthreads();

#pragma unroll
    for (int i = 0; i < KI; i++) {
        int cur = i & 1;
        uint4 bnext[4];
        if (i + 1 < KI) {
            gloadA((i + 1) * 32);
#pragma unroll
            for (int ni = 0; ni < 4; ni++)
                bnext[ni] = *(const uint4*)(brow[ni] + (i + 1) * 32);
        }

        half8_t af[4];
#pragma unroll
        for (int mi = 0; mi < 4; mi++) {
            int row = wm + mi * 16 + l16;
            if constexpr (F32) {
                const float* pl = (const float*)&As[cur][0] + row * SROW + quad * 8;
                float4 x0 = *(const float4*)pl;
                float4 x1 = *(const float4*)(pl + 4);
                half8_t h;
                h[0] = (_Float16)x0.x; h[1] = (_Float16)x0.y;
                h[2] = (_Float16)x0.z; h[3] = (_Float16)x0.w;
                h[4] = (_Float16)x1.x; h[5] = (_Float16)x1.y;
                h[6] = (_Float16)x1.z; h[7] = (_Float16)x1.w;
                af[mi] = h;
            } else {
                af[mi] = *(const half8_t*)&As[cur][row * SROW + quad * 8];
            }
        }
#pragma unroll
        for (int mi = 0; mi < 4; mi++)
#pragma unroll
            for (int ni = 0; ni < 4; ni++)
                acc[mi][ni] = __builtin_amdgcn_mfma_f32_16x16x32_f16(
                    af[mi], *(half8_t*)&bcur[ni], acc[mi][ni], 0, 0, 0);

        if (i + 1 < KI) {
            sstore(cur ^ 1);
#pragma unroll
            for (int ni = 0; ni < 4; ni++) bcur[ni] = bnext[ni];
        }
        __syncthreads();
    }

#pragma unroll
    for (int mi = 0; mi < 4; mi++) {
#pragma unroll
        for (int r = 0; r < 4; r++) {
            int rr = row0 + wm + mi * 16 + quad * 4 + r;
            if (rr < M) {
#pragma unroll
                for (int ni = 0; ni < 4; ni++) {
                    C[(size_t)rr * HH + col0 + wn + ni * 16 + l16] =
                        __float2half(acc[mi][ni][r]);
                }
            }
        }
    }
}

// ---------------- aggregation + bias + SELU (+optional skip) ----------------
__device__ inline void fma8(float* acc, uint4 raw, float w) {
    const __half2* h = (const __half2*)&raw;
#pragma unroll
    for (int i = 0; i < 4; i++) {
        float2 f = __half22float2(h[i]);
        acc[2 * i]     += w * f.x;
        acc[2 * i + 1] += w * f.y;
    }
}

__global__ __launch_bounds__(256) void agg_selu(const __half* __restrict__ T,
                                                const float* __restrict__ dis,
                                                const int* __restrict__ off,
                                                const int* __restrict__ nbr,
                                                const float* __restrict__ bias,
                                                const __half* skip, __half* out) {
    int t = threadIdx.x;
    int l32 = t & 31;
    int n = blockIdx.x * 8 + (t >> 5);
    int c = l32 * 8;
    float dn = dis[n];

    float acc[8];
#pragma unroll
    for (int i = 0; i < 8; i++) acc[i] = 0.f;
    fma8(acc, *(const uint4*)(T + (size_t)n * HH + c), dn * dn);  // self-loop

    int s0 = off[n], s1 = off[n + 1];
    for (int base = s0; base < s1; base += 32) {
        int cnt = min(32, s1 - base);
        int sidv = 0; float sdsv = 0.f;
        if (l32 < cnt) {
            sidv = nbr[base + l32];
            sdsv = dis[sidv] * dn;
        }
        int j = 0;
        for (; j + 8 <= cnt; j += 8) {
            int a0 = __shfl(sidv, j, 32),     a1 = __shfl(sidv, j + 1, 32);
            int a2 = __shfl(sidv, j + 2, 32), a3 = __shfl(sidv, j + 3, 32);
            int a4 = __shfl(sidv, j + 4, 32), a5 = __shfl(sidv, j + 5, 32);
            int a6 = __shfl(sidv, j + 6, 32), a7 = __shfl(sidv, j + 7, 32);
            float w0 = __shfl(sdsv, j, 32),     w1 = __shfl(sdsv, j + 1, 32);
            float w2 = __shfl(sdsv, j + 2, 32), w3 = __shfl(sdsv, j + 3, 32);
            float w4 = __shfl(sdsv, j + 4, 32), w5 = __shfl(sdsv, j + 5, 32);
            float w6 = __shfl(sdsv, j + 6, 32), w7 = __shfl(sdsv, j + 7, 32);
            uint4 r0 = *(const uint4*)(T + (size_t)a0 * HH + c);
            uint4 r1 = *(const uint4*)(T + (size_t)a1 * HH + c);
            uint4 r2 = *(const uint4*)(T + (size_t)a2 * HH + c);
            uint4 r3 = *(const uint4*)(T + (size_t)a3 * HH + c);
            uint4 r4 = *(const uint4*)(T + (size_t)a4 * HH + c);
            uint4 r5 = *(const uint4*)(T + (size_t)a5 * HH + c);
            uint4 r6 = *(const uint4*)(T + (size_t)a6 * HH + c);
            uint4 r7 = *(const uint4*)(T + (size_t)a7 * HH + c);
            fma8(acc, r0, w0); fma8(acc, r1, w1);
            fma8(acc, r2, w2); fma8(acc, r3, w3);
            fma8(acc, r4, w4); fma8(acc, r5, w5);
            fma8(acc, r6, w6); fma8(acc, r7, w7);
        }
        for (; j < cnt; j++) {
            int s = __shfl(sidv, j, 32);
            float w = __shfl(sdsv, j, 32);
            fma8(acc, *(const uint4*)(T + (size_t)s * HH + c), w);
        }
    }

    const float scale = 1.0507009873554805f;
    const float alpha = 1.6732632423543772f;
    float4 b0 = *(const float4*)(bias + c);
    float4 b1 = *(const float4*)(bias + c + 4);
    float bb[8] = {b0.x, b0.y, b0.z, b0.w, b1.x, b1.y, b1.z, b1.w};
    float sk8[8];
#pragma unroll
    for (int i = 0; i < 8; i++) sk8[i] = 0.f;
    if (skip) {
        uint4 raw = *(const uint4*)(skip + (size_t)n * HH + c);
        const __half2* h = (const __half2*)&raw;
#pragma unroll
        for (int i = 0; i < 4; i++) {
            float2 f = __half22float2(h[i]);
            sk8[2 * i] = f.x; sk8[2 * i + 1] = f.y;
        }
    }
    _Float16 res[8];
#pragma unroll
    for (int i = 0; i < 8; i++) {
        float v = acc[i] + bb[i];
        float r = v > 0.f ? scale * v : scale * alpha * expm1f(v);
        res[i] = (_Float16)(r + sk8[i]);
    }
    *(uint4*)(out + (size_t)n * HH + c) = *(uint4*)res;
}

// ---------------- assignment head via MFMA ----------------
__global__ __launch_bounds__(256) void assign_mfma(const __half* __restrict__ Hb,
                                                   const __half* __restrict__ WaT,
                                                   const float* __restrict__ ba,
                                                   const float* __restrict__ degf,
                                                   float* __restrict__ out_assign,
                                                   __half* __restrict__ out_f16,
                                                   float* __restrict__ scal) {
    int t = threadIdx.x;
    int wave = t >> 6, lane = t & 63, quad = lane >> 4, l16 = lane & 15;
    int nb = blockIdx.x * 256 + wave * 64;

    f32x4 acc[4] = {};
    const __half* bp = WaT + l16 * HH + quad * 8;
    const __half* ap[4];
#pragma unroll
    for (int mi = 0; mi < 4; mi++) {
        int r = nb + mi * 16 + l16;
        if (r >= NN) r = NN - 1;
        ap[mi] = Hb + (size_t)r * HH + quad * 8;
    }
#pragma unroll
    for (int s = 0; s < 8; s++) {
        half8_t bf = *(const half8_t*)(bp + s * 32);
#pragma unroll
        for (int mi = 0; mi < 4; mi++) {
            half8_t af = *(const half8_t*)(ap[mi] + s * 32);
            acc[mi] = __builtin_amdgcn_mfma_f32_16x16x32_f16(af, bf, acc[mi], 0, 0, 0);
        }
    }

    float myb = ba[l16];
    float lcs = 0.f, ldS = 0.f, lent = 0.f;
#pragma unroll
    for (int mi = 0; mi < 4; mi++) {
#pragma unroll
        for (int r = 0; r < 4; r++) {
            int node = nb + mi * 16 + quad * 4 + r;
            bool ok = node < NN;
            float logit = acc[mi][r] + myb;
            float mx = logit;
            for (int o = 1; o < 16; o <<= 1) mx = fmaxf(mx, __shfl_xor(mx, o, 16));
            float e = expf(logit - mx);
            float sum = e;
            for (int o = 1; o < 16; o <<= 1) sum += __shfl_xor(sum, o, 16);
            float a = e / sum;
            if (ok) {
                out_assign[(size_t)node * KK + l16] = a;
                out_f16[(size_t)node * KK + l16] = __float2half(a);
                lcs += a;
                ldS += degf[node] * a;
                lent += a * logf(a + 1e-8f);
            }
        }
    }
    // cs/dS: reduce across the 4 quads (same l16)
    lcs += __shfl_xor(lcs, 16); lcs += __shfl_xor(lcs, 32);
    ldS += __shfl_xor(ldS, 16); ldS += __shfl_xor(ldS, 32);
    for (int o = 32; o >= 1; o >>= 1) lent += __shfl_xor(lent, o);
    if (quad == 0) {
        atomicAdd(&scal[l16], lcs);
        atomicAdd(&scal[16 + l16], ldS);
    }
    if (lane == 0) atomicAdd(&scal[33], lent);
}

// ---------------- fused tail: edge_trace (blocks 0..781) + pooled partial (blocks 782..1581) ----
__device__ inline float dot16h(const __half* a, const __half* b) {
    uint4 a0 = *(const uint4*)a, a1 = *(const uint4*)(a + 8);
    uint4 b0 = *(const uint4*)b, b1 = *(const uint4*)(b + 8);
    float p = 0.f;
    const __half2* xa = (const __half2*)&a0;
    const __half2* xb = (const __half2*)&b0;
#pragma unroll
    for (int i = 0; i < 4; i++) {
        float2 u = __half22float2(xa[i]), v = __half22float2(xb[i]);
        p += u.x * v.x + u.y * v.y;
    }
    xa = (const __half2*)&a1; xb = (const __half2*)&b1;
#pragma unroll
    for (int i = 0; i < 4; i++) {
        float2 u = __half22float2(xa[i]), v = __half22float2(xb[i]);
        p += u.x * v.x + u.y * v.y;
    }
    return p;
}

#define PCH 125
__global__ __launch_bounds__(256) void trace_pooled(const int4* __restrict__ src4,
                                                    const int4* __restrict__ dst4,
                                                    const __half* __restrict__ Ah,
                                                    float* __restrict__ scal,
                                                    const float* __restrict__ emb,
                                                    const float* __restrict__ assign,
                                                    float* __restrict__ part) {
    __shared__ float sa[PCH * KK];  // 8 KB; sa[0] doubles as the trace scratch
    int bx = blockIdx.x, t = threadIdx.x;
    if (bx < 782) {
        // ---- edge_trace role ----
        int e = bx * 256 + t;
        float p = 0.f;
        if (e < EE / 4) {
            int4 s = src4[e], d = dst4[e];
            p += dot16h(Ah + (size_t)s.x * KK, Ah + (size_t)d.x * KK);
            p += dot16h(Ah + (size_t)s.y * KK, Ah + (size_t)d.y * KK);
            p += dot16h(Ah + (size_t)s.z * KK, Ah + (size_t)d.z * KK);
            p += dot16h(Ah + (size_t)s.w * KK, Ah + (size_t)d.w * KK);
        }
        for (int o = 32; o >= 1; o >>= 1) p += __shfl_xor(p, o);
        if (t == 0) sa[0] = 0.f;
        __syncthreads();
        if ((t & 63) == 0) atomicAdd(&sa[0], p);
        __syncthreads();
        if (t == 0) atomicAdd(&scal[32], sa[0]);
    } else {
        // ---- pooled partial role: part[by][k][d] = sum_{n in chunk} a[n][k]*emb[n][d] ----
        int j = bx - 782;
        int d = (j & 1) * 256 + t;
        int by = j >> 1;
        int c0 = by * PCH;
        float acc[KK];
#pragma unroll
        for (int k = 0; k < KK; k++) acc[k] = 0.f;
        {
            const float4* srcv = (const float4*)(assign + (size_t)c0 * KK);
            float4* dstv = (float4*)sa;
            for (int i = t; i < PCH * KK / 4; i += 256) dstv[i] = srcv[i];
        }
        __syncthreads();
        for (int jj = 0; jj < PCH; jj++) {
            float ev = emb[(size_t)(c0 + jj) * DD + d];
#pragma unroll
            for (int k4 = 0; k4 < 4; k4++) {
                float4 s4 = *(const float4*)&sa[jj * KK + k4 * 4];
                acc[k4 * 4 + 0] += s4.x * ev;
                acc[k4 * 4 + 1] += s4.y * ev;
                acc[k4 * 4 + 2] += s4.z * ev;
                acc[k4 * 4 + 3] += s4.w * ev;
            }
        }
        float* dst = part + (size_t)by * (KK * DD);
#pragma unroll
        for (int k = 0; k < KK; k++) dst[k * DD + d] = acc[k];
    }
}

// ---------------- finalize: reduce pooled partials + normalize + scalar losses ----------------
__global__ void finalize(const float* __restrict__ part, const float* __restrict__ scal,
                         float* __restrict__ out) {
    int bx = blockIdx.x, t = threadIdx.x;
    if (bx < 32) {
        int i = bx * 256 + t;  // 0..8191
        float s0 = 0.f, s1 = 0.f, s2 = 0.f, s3 = 0.f;
        for (int p = 0; p < 400; p += 4) {
            s0 += part[(size_t)p * 8192 + i];
            s1 += part[(size_t)(p + 1) * 8192 + i];
            s2 += part[(size_t)(p + 2) * 8192 + i];
            s3 += part[(size_t)(p + 3) * 8192 + i];
        }
        int k = i >> 9;  // i / DD
        out[800000 + i] = (s0 + s1 + s2 + s3) / (scal[k] + 1e-8f);
    } else if (t == 0) {
        float cs2 = 0.f, ds2 = 0.f;
        for (int k = 0; k < KK; k++) {
            cs2 += scal[k] * scal[k];
            ds2 += scal[16 + k] * scal[16 + k];
        }
        float two_m = (float)EE;  // sum(degrees) == E, 2m == E
        float normalizer = ds2 / two_m;
        float trace = scal[32];
        float spectral = -(trace - (float)KK * normalizer) / two_m;
        float collapse = sqrtf(cs2) / (float)NN * 4.0f - 1.0f;  // sqrt(K)=4
        float entl = 0.1f * scal[33] / (float)NN;
        out[808192] = spectral;
        out[808193] = collapse;  // COLLAPSE_REG = 1.0
        out[808194] = spectral + collapse + entl;
        out[808195] = entl;
    }
}

extern "C" void kernel_launch(void* const* d_in, const int* in_sizes, int n_in,
                              void* d_out, int out_size, void* d_ws, size_t ws_size,
                              hipStream_t stream) {
    const float* emb = (const float*)d_in[0];
    const int* esrc  = (const int*)d_in[1];
    const int* edst  = (const int*)d_in[2];
    const float* W1  = (const float*)d_in[3];
    const float* b1  = (const float*)d_in[4];
    const float* W2  = (const float*)d_in[5];
    const float* b2  = (const float*)d_in[6];
    const float* Wa  = (const float*)d_in[7];
    const float* ba  = (const float*)d_in[8];
    float* out = (float*)d_out;

    // workspace layout (4B units unless noted) — total ~56 MB
    int* indeg      = (int*)d_ws;            // 50000
    int* outdeg     = indeg + 50000;         // 50000
    int* cur        = outdeg + 50000;        // 50000
    float* pool_acc = (float*)(cur + 50000); // 8192 (unused, kept for layout)
    float* scal     = pool_acc + 8192;       // 64
    int* part       = (int*)(scal + 64);     // 256 (scan partials)
    int* off        = part + 256;            // 50001 (+pad to 50004)
    int* nbr        = off + 50004;           // 800000
    float* dis      = (float*)(nbr + 800000);// 50000
    float* degf     = dis + 50000;           // 50000
    __half* Wt1     = (__half*)(degf + 50000);   // 256*512 f16
    __half* Wt2     = Wt1 + 256 * 512;           // 256*256 f16
    __half* WaT     = Wt2 + 256 * 256;           // 16*256 f16
    __half* T       = WaT + 16 * 256;            // 50000*256 f16 (25.6 MB)
    __half* Hb      = T + (size_t)NN * HH;       // 50000*256 f16 (25.6 MB)
    __half* Ah      = T;  // f16 assignments alias T (dead after agg2)
    float* pool_part = (float*)Hb;  // 400*8192 f32 = 13.1 MB, Hb dead after assign_mfma

    // zero the atomically-accumulated region: indeg/outdeg/cur/pool_acc/scal
    zero_kernel<<<dim3(619), 256, 0, stream>>>((int*)d_ws, 158256);
    count_kernel<<<dim3(782), 256, 0, stream>>>((const int4*)esrc, (const int4*)edst,
                                                indeg, outdeg);

    // CSR offsets: 3-phase scan (+ dis/degf in p1)
    scan_p1<<<dim3(NB_SCAN), 256, 0, stream>>>(indeg, part, NN, outdeg, dis, degf);
    scan_p2<<<dim3(1), 256, 0, stream>>>(part, NB_SCAN, off + NN);
    scan_p3<<<dim3(NB_SCAN), 256, 0, stream>>>(indeg, part, off, NN);

    // weights -> f16 transposed, IMMEDIATELY before gemm1 (keeps Wt1/Wt2 hot in L2)
    transpose_w<<<dim3(784), 256, 0, stream>>>(W1, Wt1, W2, Wt2, Wa, WaT);

    // conv1 GEMM fused with CSR scatter (independent; scatter hides in gemm's idle slots)
    gemm1_scatter<<<dim3(1566), 256, 0, stream>>>(emb, Wt1, T, NN,
                                                  (const int4*)esrc, (const int4*)edst,
                                                  off, cur, nbr);
    agg_selu<<<dim3(6250), 256, 0, stream>>>(T, dis, off, nbr, b1, nullptr, Hb);

    // conv2: T = Hb @ W2 ; Hb = selu(Ahat*T + b2) + Hb (skip, in place)
    mfma_gemm<__half, HH><<<dim3(392, 2), 256, 0, stream>>>(Hb, Wt2, T, NN);
    agg_selu<<<dim3(6250), 256, 0, stream>>>(T, dis, off, nbr, b2, Hb, Hb);

    // head: assignments -> d_out[0..800000) (+f16 copy), loss partials
    assign_mfma<<<dim3(196), 256, 0, stream>>>(Hb, WaT, ba, degf, out, Ah, scal);
    // fused tail: trace (782 blocks) overlapped with pooled partials (800 blocks)
    trace_pooled<<<dim3(1582), 256, 0, stream>>>((const int4*)esrc, (const int4*)edst,
                                                 Ah, scal, emb, out, pool_part);
    finalize<<<dim3(33), 256, 0, stream>>>(pool_part, scal, out);
}